// Round 7
// baseline (1024.285 us; speedup 1.0000x reference)
//
#include <hip/hip_runtime.h>

#define B_TREES 128
#define NPT 255
#define NTOT (B_TREES * NPT)   // 32640
#define FIN 64
#define HH 256

typedef short bf16x8 __attribute__((ext_vector_type(8)));
typedef float f32x4  __attribute__((ext_vector_type(4)));
typedef unsigned short u16;

__device__ __forceinline__ float sigf(float x) {
    return __frcp_rn(1.0f + __expf(-x));
}
__device__ __forceinline__ float tanh_fast(float x) {
    return __builtin_fmaf(2.0f, sigf(2.0f * x), -1.0f);
}
__device__ __forceinline__ u16 bf_hi(float v) {       // round-to-nearest-even bf16
    unsigned u = __float_as_uint(v);
    return (u16)((u + 0x7FFFu + ((u >> 16) & 1u)) >> 16);
}
__device__ __forceinline__ float bf_f(u16 b) { return __uint_as_float(((unsigned)b) << 16); }

// ---------------------------------------------------------------------------
// B pack: B[576 x 1280] in MFMA-B-frag layout, split into bf16 hi + lo.
// ---------------------------------------------------------------------------
__global__ __launch_bounds__(256) void pack_B(
    const float* __restrict__ Uiou, const float* __restrict__ Uf,
    const float* __restrict__ Wiou, const float* __restrict__ Wf,
    u16* __restrict__ Bhi, u16* __restrict__ Blo)
{
    int idx = blockIdx.x * 256 + threadIdx.x;   // < 80*10*64*8 = 409600
    int j    = idx & 7;
    int lane = (idx >> 3) & 63;
    int ksl  = (idx >> 9) % 10;
    int ct   = idx / 5120;
    int s = ct % 5, hb = ct / 5;
    int n = lane & 15, q = lane >> 4;
    int jH = hb * 16 + n;
    int k = (s < 4 ? ksl * 32 : 320 + ksl * 32) + q * 8 + j;

    float v = 0.0f;
    if (s == 4) {
        if (k < 576) v = Uf[(size_t)jH * HH + (k - 320)];
    } else {
        if (k < 256) {
            v = (s < 3) ? Uiou[(size_t)(s * 256 + jH) * HH + k]
                        : Uf[(size_t)jH * HH + k];
        } else {
            int kw = k - 256;
            v = (s < 3) ? Wiou[(size_t)(s * 256 + jH) * FIN + kw]
                        : 2.0f * Wf[(size_t)jH * FIN + kw];
        }
    }
    u16 hi = bf_hi(v);
    u16 lo = bf_hi(v - bf_f(hi));
    Bhi[idx] = hi;
    Blo[idx] = lo;
}

// ---------------------------------------------------------------------------
// Flat K-step decode: step s -> (G, ctl, B-kslot, A-kslot).
// ---------------------------------------------------------------------------
template<int NCT, bool LEAF>
__device__ __forceinline__ void kdecode(int s, int& G, int& ctl, int& sgB, int& sgA)
{
    constexpr int SUBS = NCT / 5;
    constexpr int TPG  = LEAF ? SUBS * 3 : SUBS * 4;
    constexpr int MAINS = (LEAF ? 2 : 10) * TPG;
    if (s < MAINS) {
        int g = s / TPG, tl = s % TPG;
        G = (LEAF ? 8 : 0) + g;
        ctl = LEAF ? (tl / 3) * 5 + (tl % 3) : (tl / 4) * 5 + (tl % 4);
        sgB = G;
        sgA = LEAF ? (G - 8) : G;
    } else {
        int s2 = s - MAINS;
        G = 10 + s2 / SUBS;
        ctl = (s2 % SUBS) * 5 + 4;
        sgB = G - 10;
        sgA = G;
    }
}

// ---------------------------------------------------------------------------
// One level unit (32 rows x (1280/CSPLIT) cols). Verbatim round-1 body.
// ---------------------------------------------------------------------------
template<int NCT, bool LEAF>
__device__ void do_level(int unit, char* smem,
    const float* __restrict__ feat,
    const u16* __restrict__ Bhi, const u16* __restrict__ Blo,
    const float* __restrict__ biou, const float* __restrict__ bfv,
    float* __restrict__ h, float* __restrict__ c,
    int Lt, int lg)
{
    constexpr int CSPLIT = 20 / NCT;
    constexpr int SUBS = NCT / 5;
    constexpr int KSTR = LEAF ? 2 : 18;                 // A kslot stride per row-tile
    short* Ahi = (short*)smem;
    short* Alo = (short*)(smem + (LEAF ? 4096 : 36864));

    const int tid = threadIdx.x;
    const int lane = tid & 63, w = tid >> 6;
    const int cs = unit % CSPLIT;
    const int rb = unit / CSPLIT;
    const int m0 = rb * 32;
    const int msk = (1 << lg) - 1;
    const int ctbase = cs * 4 * NCT + w * NCT;

    const float4* Hf4 = (const float4*)h;
    const float4* Ff4 = (const float4*)feat;

    // ---- stage A ----
    if constexpr (!LEAF) {
        for (int rep = 0; rep < 8; ++rep) {            // hs/hd: 32 m x 64 float4
            int flat = rep * 256 + tid;
            int m = flat >> 6, f4 = flat & 63;
            int mg = m0 + m;
            int b = mg >> lg, ii = Lt + (mg & msk);
            int gc = b * NPT + 2 * ii + 1;
            float4 h1 = Hf4[(size_t)gc * 64 + f4];
            float4 h2 = Hf4[(size_t)(gc + 1) * 64 + f4];
            float hsv[4] = {h1.x + h2.x, h1.y + h2.y, h1.z + h2.z, h1.w + h2.w};
            float hdv[4] = {h1.x - h2.x, h1.y - h2.y, h1.z - h2.z, h1.w - h2.w};
            int rt = m >> 4, lm = m & 15;
            int ks = f4 >> 3;
            int lane_ = lm + 16 * ((f4 >> 1) & 3);
            int j0 = (f4 & 1) * 4;
            ushort4 sh, sl, dh, dl;
            u16* shp = (u16*)&sh; u16* slp = (u16*)&sl;
            u16* dhp = (u16*)&dh; u16* dlp = (u16*)&dl;
#pragma unroll
            for (int e = 0; e < 4; ++e) {
                u16 a = bf_hi(hsv[e]); shp[e] = a; slp[e] = bf_hi(hsv[e] - bf_f(a));
                u16 d = bf_hi(hdv[e]); dhp[e] = d; dlp[e] = bf_hi(hdv[e] - bf_f(d));
            }
            int base_s = ((rt * 18 + ks) * 64 + lane_) * 8 + j0;        // hs at kstep ks
            int base_d = ((rt * 18 + ks + 10) * 64 + lane_) * 8 + j0;   // hd at kstep ks+10
            *(ushort4*)&Ahi[base_s] = sh;  *(ushort4*)&Alo[base_s] = sl;
            *(ushort4*)&Ahi[base_d] = dh;  *(ushort4*)&Alo[base_d] = dl;
        }
    }
    for (int rep = 0; rep < 2; ++rep) {                // x: 32 m x 16 float4
        int flat = rep * 256 + tid;
        int m = flat >> 4, f4 = flat & 15;
        int mg = m0 + m;
        int b = mg >> lg, ii = Lt + (mg & msk);
        int g = b * NPT + ii;
        float4 x4 = Ff4[(size_t)g * 16 + f4];
        float xv[4] = {x4.x, x4.y, x4.z, x4.w};
        int rt = m >> 4, lm = m & 15;
        int ks = (LEAF ? 0 : 8) + (f4 >> 3);
        int lane_ = lm + 16 * ((f4 >> 1) & 3);
        int j0 = (f4 & 1) * 4;
        ushort4 xh, xl;
        u16* xhp = (u16*)&xh; u16* xlp = (u16*)&xl;
#pragma unroll
        for (int e = 0; e < 4; ++e) {
            u16 a = bf_hi(xv[e]); xhp[e] = a; xlp[e] = bf_hi(xv[e] - bf_f(a));
        }
        int base = ((rt * KSTR + ks) * 64 + lane_) * 8 + j0;
        *(ushort4*)&Ahi[base] = xh;  *(ushort4*)&Alo[base] = xl;
    }
    __syncthreads();

    // ---- K loop (flat, software-pipelined) ----
    constexpr int TPG    = LEAF ? SUBS * 3 : SUBS * 4;
    constexpr int MAINS  = (LEAF ? 2 : 10) * TPG;
    constexpr int NSTEPS = LEAF ? MAINS : MAINS + 8 * SUBS;
    constexpr int NB = 6, PD = 5;                       // 6 rotating bufs, 5-deep prefetch
    constexpr int GLAST = LEAF ? 9 : 17;

    f32x4 acc[2][NCT];
#pragma unroll
    for (int rt = 0; rt < 2; ++rt)
#pragma unroll
        for (int i = 0; i < NCT; ++i) acc[rt][i] = (f32x4){0.f, 0.f, 0.f, 0.f};

    const u16* Bw_h = Bhi + (size_t)ctbase * 5120 + (size_t)lane * 8;
    const u16* Bw_l = Blo + (size_t)ctbase * 5120 + (size_t)lane * 8;
    const short* Ah0 = Ahi + lane * 8;
    const short* Al0 = Alo + lane * 8;

    bf16x8 bh[NB], bl[NB];
    bf16x8 pah[2][2], pal[2][2];

#pragma unroll
    for (int rt = 0; rt < 2; ++rt) {
        pah[0][rt] = *(const bf16x8*)&Ah0[(rt * KSTR + 0) * 512];
        pal[0][rt] = *(const bf16x8*)&Al0[(rt * KSTR + 0) * 512];
    }
#pragma unroll
    for (int p = 0; p < PD; ++p) {
        if (p < NSTEPS) {
            int G2, c2, b2, a2;
            kdecode<NCT, LEAF>(p, G2, c2, b2, a2);
            int off = (c2 * 10 + b2) * 512;
            bh[p % NB] = *(const bf16x8*)(Bw_h + off);
            bl[p % NB] = *(const bf16x8*)(Bw_l + off);
        }
    }

#pragma unroll
    for (int s = 0; s < NSTEPS; ++s) {
        int G, ctl, sgB, sgA;
        kdecode<NCT, LEAF>(s, G, ctl, sgB, sgA);
        bool firstG = (s < MAINS) ? (s % TPG == 0) : (((s - MAINS) % SUBS) == 0);
        if (firstG && G < GLAST) {
            int sgAn = LEAF ? (G - 7) : (G + 1);
            int parn = (G + 1) & 1;
#pragma unroll
            for (int rt = 0; rt < 2; ++rt) {
                pah[parn][rt] = *(const bf16x8*)&Ah0[(rt * KSTR + sgAn) * 512];
                pal[parn][rt] = *(const bf16x8*)&Al0[(rt * KSTR + sgAn) * 512];
            }
        }
        if (s + PD < NSTEPS) {
            int G2, c2, b2, a2;
            kdecode<NCT, LEAF>(s + PD, G2, c2, b2, a2);
            int off = (c2 * 10 + b2) * 512;
            bh[(s + PD) % NB] = *(const bf16x8*)(Bw_h + off);
            bl[(s + PD) % NB] = *(const bf16x8*)(Bw_l + off);
        }
        int par = G & 1;
#pragma unroll
        for (int rt = 0; rt < 2; ++rt) {
            acc[rt][ctl] = __builtin_amdgcn_mfma_f32_16x16x32_bf16(pah[par][rt], bh[s % NB], acc[rt][ctl], 0, 0, 0);
            acc[rt][ctl] = __builtin_amdgcn_mfma_f32_16x16x32_bf16(pah[par][rt], bl[s % NB], acc[rt][ctl], 0, 0, 0);
            acc[rt][ctl] = __builtin_amdgcn_mfma_f32_16x16x32_bf16(pal[par][rt], bh[s % NB], acc[rt][ctl], 0, 0, 0);
        }
    }
    __syncthreads();    // all waves done with A region; alias epilogue scratch over it

    // ---- epilogue (wave-private) ----
    float* sc = (float*)smem + w * 2592;       // [32 rows][81] fp32 per wave
    const int n = lane & 15, q = lane >> 4;
#pragma unroll
    for (int sub = 0; sub < SUBS; ++sub) {
#pragma unroll
        for (int rt = 0; rt < 2; ++rt)
#pragma unroll
            for (int s = 0; s < (LEAF ? 3 : 5); ++s) {
                f32x4 v = acc[rt][sub * 5 + s];
#pragma unroll
                for (int r = 0; r < 4; ++r)
                    sc[(rt * 16 + q * 4 + r) * 81 + s * 16 + n] = v[r];
            }
        int hb_abs = ctbase / 5 + sub;
        int jHb = hb_abs * 16;

        float c1v[8], c2v[8];
        if constexpr (!LEAF) {
#pragma unroll
            for (int it = 0; it < 8; ++it) {
                int idx = it * 64 + lane;
                int m = idx >> 4, jl = idx & 15;
                int jH = jHb + jl;
                int mg = m0 + m;
                int b = mg >> lg, ii = Lt + (mg & msk);
                size_t g = (size_t)b * NPT + ii;
                size_t gc = g + ii + 1;         // b*NPT + 2*ii + 1
                c1v[it] = c[gc * HH + jH];
                c2v[it] = c[(gc + 1) * HH + jH];
            }
        }
#pragma unroll
        for (int it = 0; it < 8; ++it) {
            int idx = it * 64 + lane;           // 512 items: 32 m x 16 jl
            int m = idx >> 4, jl = idx & 15;
            int jH = jHb + jl;
            float Ci  = sc[m * 81 + jl];
            float Co  = sc[m * 81 + 16 + jl];
            float Cu  = sc[m * 81 + 32 + jl];
            int mg = m0 + m;
            int b = mg >> lg, ii = Lt + (mg & msk);
            size_t g = (size_t)b * NPT + ii;
            float iv = sigf(Ci + biou[jH]);
            float ov = sigf(Co + biou[256 + jH]);
            float uv = tanh_fast(Cu + biou[512 + jH]);
            float cv;
            if constexpr (LEAF) {
                cv = iv * uv;
            } else {
                float Cfs = sc[m * 81 + 48 + jl];
                float Cfd = sc[m * 81 + 64 + jl];
                float bF = bfv[jH];
                float f1 = sigf(0.5f * (Cfs + Cfd) + bF);
                float f2 = sigf(0.5f * (Cfs - Cfd) + bF);
                cv = iv * uv + f1 * c1v[it] + f2 * c2v[it];
            }
            float hv = ov * tanh_fast(cv);
            c[g * HH + jH] = cv;
            h[g * HH + jH] = hv;
        }
    }
}

// ---------------------------------------------------------------------------
// Standalone level kernel (big levels: leaf, t1, t2).
// ---------------------------------------------------------------------------
template<int NCT, bool LEAF>
__global__ __launch_bounds__(256, LEAF ? 3 : 2) void level_mfma(
    const float* __restrict__ feat,
    const u16* __restrict__ Bhi, const u16* __restrict__ Blo,
    const float* __restrict__ biou, const float* __restrict__ bfv,
    float* __restrict__ h, float* __restrict__ c,
    int Lt, int lg)
{
    __shared__ char smem[LEAF ? 41472 : 73728];
    do_level<NCT, LEAF>(blockIdx.x, smem, feat, Bhi, Blo, biou, bfv, h, c, Lt, lg);
}

// ---------------------------------------------------------------------------
// Per-tree level: one block owns one tree; M (<=16) nodes at ii=Lt..Lt+M-1.
// Each wave covers 20 col-tiles (NCT=20, RT=1). Same per-element K-order and
// gate math as do_level -> bit-identical. Children h/c were written by THIS
// block (or by an earlier kernel for t3) -> __syncthreads() is the only sync.
// LDS: Ahi[18][64][8] @0 (18KB), Alo @18KB (total 36.9KB); epilogue scratch
// aliases @0 (per wave 16x81 fp32 = 5.2KB x 4 waves = 20.7KB).
// ---------------------------------------------------------------------------
__device__ void do_tree_level(int btree, int M, int Lt, char* smem,
    const float* __restrict__ feat,
    const u16* __restrict__ Bhi, const u16* __restrict__ Blo,
    const float* __restrict__ biou, const float* __restrict__ bfv,
    float* __restrict__ h, float* __restrict__ c)
{
    constexpr int NCT = 20;
    constexpr int SUBS = 4;
    short* Ahi = (short*)smem;
    short* Alo = (short*)(smem + 18432);

    __syncthreads();                         // prior level's scratch reads done

    const int tid = threadIdx.x;
    const int lane = tid & 63, w = tid >> 6;
    const int ctbase = w * NCT;

    const float4* Hf4 = (const float4*)h;
    const float4* Ff4 = (const float4*)feat;

    // ---- stage A: hs/hd (M x 64 float4), kslots 0..7 and 10..17 ----
    for (int flat = tid; flat < M * 64; flat += 256) {
        int m = flat >> 6, f4 = flat & 63;
        int ii = Lt + m;
        int gc = btree * NPT + 2 * ii + 1;
        float4 h1 = Hf4[(size_t)gc * 64 + f4];
        float4 h2 = Hf4[(size_t)(gc + 1) * 64 + f4];
        float hsv[4] = {h1.x + h2.x, h1.y + h2.y, h1.z + h2.z, h1.w + h2.w};
        float hdv[4] = {h1.x - h2.x, h1.y - h2.y, h1.z - h2.z, h1.w - h2.w};
        int ks = f4 >> 3;
        int lane_ = m + 16 * ((f4 >> 1) & 3);
        int j0 = (f4 & 1) * 4;
        ushort4 sh, sl, dh, dl;
        u16* shp = (u16*)&sh; u16* slp = (u16*)&sl;
        u16* dhp = (u16*)&dh; u16* dlp = (u16*)&dl;
#pragma unroll
        for (int e = 0; e < 4; ++e) {
            u16 a = bf_hi(hsv[e]); shp[e] = a; slp[e] = bf_hi(hsv[e] - bf_f(a));
            u16 d = bf_hi(hdv[e]); dhp[e] = d; dlp[e] = bf_hi(hdv[e] - bf_f(d));
        }
        int base_s = (ks * 64 + lane_) * 8 + j0;
        int base_d = ((ks + 10) * 64 + lane_) * 8 + j0;
        *(ushort4*)&Ahi[base_s] = sh;  *(ushort4*)&Alo[base_s] = sl;
        *(ushort4*)&Ahi[base_d] = dh;  *(ushort4*)&Alo[base_d] = dl;
    }
    // ---- stage A: x rows (M x 16 float4), kslots 8..9 ----
    for (int flat = tid; flat < M * 16; flat += 256) {
        int m = flat >> 4, f4 = flat & 15;
        int g = btree * NPT + Lt + m;
        float4 x4 = Ff4[(size_t)g * 16 + f4];
        float xv[4] = {x4.x, x4.y, x4.z, x4.w};
        int ks = 8 + (f4 >> 3);
        int lane_ = m + 16 * ((f4 >> 1) & 3);
        int j0 = (f4 & 1) * 4;
        ushort4 xh, xl;
        u16* xhp = (u16*)&xh; u16* xlp = (u16*)&xl;
#pragma unroll
        for (int e = 0; e < 4; ++e) {
            u16 a = bf_hi(xv[e]); xhp[e] = a; xlp[e] = bf_hi(xv[e] - bf_f(a));
        }
        int base = (ks * 64 + lane_) * 8 + j0;
        *(ushort4*)&Ahi[base] = xh;  *(ushort4*)&Alo[base] = xl;
    }
    __syncthreads();

    // ---- K loop (flat, software-pipelined; RT=1) ----
    constexpr int TPG    = SUBS * 4;         // 16
    constexpr int MAINS  = 10 * TPG;         // 160
    constexpr int NSTEPS = MAINS + 8 * SUBS; // 192
    constexpr int NB = 6, PD = 5;
    constexpr int GLAST = 17;

    f32x4 acc[NCT];
#pragma unroll
    for (int i = 0; i < NCT; ++i) acc[i] = (f32x4){0.f, 0.f, 0.f, 0.f};

    const u16* Bw_h = Bhi + (size_t)ctbase * 5120 + (size_t)lane * 8;
    const u16* Bw_l = Blo + (size_t)ctbase * 5120 + (size_t)lane * 8;
    const short* Ah0 = Ahi + lane * 8;
    const short* Al0 = Alo + lane * 8;

    bf16x8 bh[NB], bl[NB];
    bf16x8 pah[2], pal[2];

    pah[0] = *(const bf16x8*)&Ah0[0];
    pal[0] = *(const bf16x8*)&Al0[0];
#pragma unroll
    for (int p = 0; p < PD; ++p) {
        int G2, c2, b2, a2;
        kdecode<NCT, false>(p, G2, c2, b2, a2);
        int off = (c2 * 10 + b2) * 512;
        bh[p % NB] = *(const bf16x8*)(Bw_h + off);
        bl[p % NB] = *(const bf16x8*)(Bw_l + off);
    }

#pragma unroll
    for (int s = 0; s < NSTEPS; ++s) {
        int G, ctl, sgB, sgA;
        kdecode<NCT, false>(s, G, ctl, sgB, sgA);
        bool firstG = (s < MAINS) ? (s % TPG == 0) : (((s - MAINS) % SUBS) == 0);
        if (firstG && G < GLAST) {
            int parn = (G + 1) & 1;
            pah[parn] = *(const bf16x8*)&Ah0[(G + 1) * 512];
            pal[parn] = *(const bf16x8*)&Al0[(G + 1) * 512];
        }
        if (s + PD < NSTEPS) {
            int G2, c2, b2, a2;
            kdecode<NCT, false>(s + PD, G2, c2, b2, a2);
            int off = (c2 * 10 + b2) * 512;
            bh[(s + PD) % NB] = *(const bf16x8*)(Bw_h + off);
            bl[(s + PD) % NB] = *(const bf16x8*)(Bw_l + off);
        }
        int par = G & 1;
        acc[ctl] = __builtin_amdgcn_mfma_f32_16x16x32_bf16(pah[par], bh[s % NB], acc[ctl], 0, 0, 0);
        acc[ctl] = __builtin_amdgcn_mfma_f32_16x16x32_bf16(pah[par], bl[s % NB], acc[ctl], 0, 0, 0);
        acc[ctl] = __builtin_amdgcn_mfma_f32_16x16x32_bf16(pal[par], bh[s % NB], acc[ctl], 0, 0, 0);
    }
    __syncthreads();    // all waves done with A region; alias scratch over it

    // ---- epilogue (wave-private, rows 0..M-1) ----
    float* sc = (float*)smem + w * 1296;       // [16 rows][81] fp32 per wave
    const int n = lane & 15, q = lane >> 4;
    const int iters = (M * 16 + 63) / 64;
#pragma unroll
    for (int sub = 0; sub < SUBS; ++sub) {
#pragma unroll
        for (int s = 0; s < 5; ++s) {
            f32x4 v = acc[sub * 5 + s];
#pragma unroll
            for (int r = 0; r < 4; ++r)
                sc[(q * 4 + r) * 81 + s * 16 + n] = v[r];
        }
        int hb_abs = w * SUBS + sub;           // = ctbase/5 + sub
        int jHb = hb_abs * 16;

        float c1v[4], c2v[4];
        for (int it = 0; it < iters; ++it) {   // prefetch children c
            int idx = it * 64 + lane;
            if (idx < M * 16) {
                int m = idx >> 4, jl = idx & 15;
                int jH = jHb + jl;
                int ii = Lt + m;
                size_t g = (size_t)btree * NPT + ii;
                size_t gc = g + ii + 1;        // btree*NPT + 2*ii + 1
                c1v[it] = c[gc * HH + jH];
                c2v[it] = c[(gc + 1) * HH + jH];
            }
        }
        for (int it = 0; it < iters; ++it) {
            int idx = it * 64 + lane;
            if (idx < M * 16) {
                int m = idx >> 4, jl = idx & 15;
                int jH = jHb + jl;
                int ii = Lt + m;
                size_t g = (size_t)btree * NPT + ii;
                float Ci  = sc[m * 81 + jl];
                float Co  = sc[m * 81 + 16 + jl];
                float Cu  = sc[m * 81 + 32 + jl];
                float Cfs = sc[m * 81 + 48 + jl];
                float Cfd = sc[m * 81 + 64 + jl];
                float iv = sigf(Ci + biou[jH]);
                float ov = sigf(Co + biou[256 + jH]);
                float uv = tanh_fast(Cu + biou[512 + jH]);
                float bF = bfv[jH];
                float f1 = sigf(0.5f * (Cfs + Cfd) + bF);
                float f2 = sigf(0.5f * (Cfs - Cfd) + bF);
                float cv = iv * uv + f1 * c1v[it] + f2 * c2v[it];
                float hv = ov * tanh_fast(cv);
                c[g * HH + jH] = cv;
                h[g * HH + jH] = hv;
            }
        }
    }
}

// ---------------------------------------------------------------------------
// Tree tail: t3..t7 + head, one block per tree, NO grid sync.
// ---------------------------------------------------------------------------
__global__ __launch_bounds__(256, 2) void tree_tail(
    const float* __restrict__ feat,
    const u16* __restrict__ Bhi, const u16* __restrict__ Blo,
    const float* __restrict__ biou, const float* __restrict__ bfv,
    const float* __restrict__ l0w,  const float* __restrict__ l0b,
    const float* __restrict__ l1w,  const float* __restrict__ l1b,
    float* __restrict__ out,
    float* __restrict__ h, float* __restrict__ c)
{
    __shared__ char smem[36864];
    const int btree = blockIdx.x;
    const int tid = threadIdx.x;

    const int LtA[5] = {15, 7, 3, 1, 0};
    const int MA[5]  = {16, 8, 4, 2, 1};
#pragma unroll 1
    for (int lv = 0; lv < 5; ++lv)
        do_tree_level(btree, MA[lv], LtA[lv], smem, feat, Bhi, Blo, biou, bfv, h, c);

    __syncthreads();

    // ---- head: 256 threads, bit-identical accumulation grouping ----
    float* ms  = (float*)smem;         // 256 floats
    float* red = ms + HH;              // 4 floats
    const int j = tid;
    const float* hb = h + (size_t)btree * NPT * HH;

    float a0 = 0.f, a1 = 0.f, a2 = 0.f, a3 = 0.f;
    int i = 0;
    for (; i + 3 < NPT; i += 4) {
        a0 += hb[(size_t)(i    ) * HH + j];
        a1 += hb[(size_t)(i + 1) * HH + j];
        a2 += hb[(size_t)(i + 2) * HH + j];
        a3 += hb[(size_t)(i + 3) * HH + j];
    }
    a0 += hb[(size_t)252 * HH + j];
    a1 += hb[(size_t)253 * HH + j];
    a2 += hb[(size_t)254 * HH + j];
    ms[j] = (a0 + a1 + a2 + a3) * (1.0f / (float)NPT);
    __syncthreads();

    const float4* L0 = (const float4*)(l0w + (size_t)j * HH);
    const float4* M4 = (const float4*)ms;
    float y0 = 0.f, y1 = 0.f, y2 = 0.f, y3 = 0.f;
    for (int k4 = 0;  k4 < 16; ++k4) { float4 wv = L0[k4]; float4 m4 = M4[k4]; y0 += wv.x * m4.x + wv.y * m4.y + wv.z * m4.z + wv.w * m4.w; }
    for (int k4 = 16; k4 < 32; ++k4) { float4 wv = L0[k4]; float4 m4 = M4[k4]; y1 += wv.x * m4.x + wv.y * m4.y + wv.z * m4.z + wv.w * m4.w; }
    for (int k4 = 32; k4 < 48; ++k4) { float4 wv = L0[k4]; float4 m4 = M4[k4]; y2 += wv.x * m4.x + wv.y * m4.y + wv.z * m4.z + wv.w * m4.w; }
    for (int k4 = 48; k4 < 64; ++k4) { float4 wv = L0[k4]; float4 m4 = M4[k4]; y3 += wv.x * m4.x + wv.y * m4.y + wv.z * m4.z + wv.w * m4.w; }
    float yy = y0 + y1 + y2 + y3 + l0b[j];
    yy = fmaxf(yy, 0.f);
    float v = yy * l1w[j];
    for (int off = 32; off > 0; off >>= 1) v += __shfl_down(v, off, 64);
    if ((j & 63) == 0) red[j >> 6] = v;
    __syncthreads();
    if (tid == 0) out[btree] = red[0] + red[1] + red[2] + red[3] + l1b[0];
}

// ---------------------------------------------------------------------------
extern "C" void kernel_launch(void* const* d_in, const int* in_sizes, int n_in,
                              void* d_out, int out_size, void* d_ws, size_t ws_size,
                              hipStream_t stream)
{
    const float* feat = (const float*)d_in[0];
    const float* Wiou = (const float*)d_in[4];
    const float* biou = (const float*)d_in[5];
    const float* Uiou = (const float*)d_in[6];
    const float* Wf   = (const float*)d_in[7];
    const float* bfv  = (const float*)d_in[8];
    const float* Uf   = (const float*)d_in[9];
    const float* l0w  = (const float*)d_in[10];
    const float* l0b  = (const float*)d_in[11];
    const float* l1w  = (const float*)d_in[12];
    const float* l1b  = (const float*)d_in[13];

    float* h = (float*)d_ws;
    float* c = h + (size_t)NTOT * HH;
    u16* Bhi = (u16*)(c + (size_t)NTOT * HH);
    u16* Blo = Bhi + 409600;

    // pack weights (every launch; ws is re-poisoned by harness)
    pack_B<<<1600, 256, 0, stream>>>(Uiou, Uf, Wiou, Wf, Bhi, Blo);

    // leaves: M=16384, NCT=10 (CSPLIT=2) -> 1024 blocks, 3 blocks/CU
    level_mfma<10, true><<<1024, 256, 0, stream>>>(feat, Bhi, Blo, biou, bfv, h, c, 127, 7);
    // t=1: M=8192, NCT=10 -> 512 blocks
    level_mfma<10, false><<<512, 256, 0, stream>>>(feat, Bhi, Blo, biou, bfv, h, c, 63, 6);
    // t=2: NCT=5 (CSPLIT=4) -> 512 blocks
    level_mfma<5, false><<<512, 256, 0, stream>>>(feat, Bhi, Blo, biou, bfv, h, c, 31, 5);

    // t=3..7 + head: one block per tree, no grid sync
    tree_tail<<<B_TREES, 256, 0, stream>>>(feat, Bhi, Blo, biou, bfv,
                                           l0w, l0b, l1w, l1b, (float*)d_out,
                                           h, c);
}

// Round 8
// 515.421 us; speedup vs baseline: 1.9873x; 1.9873x over previous
//
#include <hip/hip_runtime.h>

#define B_TREES 128
#define NPT 255
#define NTOT (B_TREES * NPT)   // 32640
#define FIN 64
#define HH 256

typedef short bf16x8 __attribute__((ext_vector_type(8)));
typedef float f32x4  __attribute__((ext_vector_type(4)));
typedef unsigned short u16;

__device__ __forceinline__ float sigf(float x) {
    return __frcp_rn(1.0f + __expf(-x));
}
__device__ __forceinline__ float tanh_fast(float x) {
    return __builtin_fmaf(2.0f, sigf(2.0f * x), -1.0f);
}
__device__ __forceinline__ u16 bf_hi(float v) {       // round-to-nearest-even bf16
    unsigned u = __float_as_uint(v);
    return (u16)((u + 0x7FFFu + ((u >> 16) & 1u)) >> 16);
}
__device__ __forceinline__ float bf_f(u16 b) { return __uint_as_float(((unsigned)b) << 16); }

// ---------------------------------------------------------------------------
// B pack: B[576 x 1280] in MFMA-B-frag layout, split into bf16 hi + lo.
// ---------------------------------------------------------------------------
__global__ __launch_bounds__(256) void pack_B(
    const float* __restrict__ Uiou, const float* __restrict__ Uf,
    const float* __restrict__ Wiou, const float* __restrict__ Wf,
    u16* __restrict__ Bhi, u16* __restrict__ Blo)
{
    int idx = blockIdx.x * 256 + threadIdx.x;   // < 80*10*64*8 = 409600
    int j    = idx & 7;
    int lane = (idx >> 3) & 63;
    int ksl  = (idx >> 9) % 10;
    int ct   = idx / 5120;
    int s = ct % 5, hb = ct / 5;
    int n = lane & 15, q = lane >> 4;
    int jH = hb * 16 + n;
    int k = (s < 4 ? ksl * 32 : 320 + ksl * 32) + q * 8 + j;

    float v = 0.0f;
    if (s == 4) {
        if (k < 576) v = Uf[(size_t)jH * HH + (k - 320)];
    } else {
        if (k < 256) {
            v = (s < 3) ? Uiou[(size_t)(s * 256 + jH) * HH + k]
                        : Uf[(size_t)jH * HH + k];
        } else {
            int kw = k - 256;
            v = (s < 3) ? Wiou[(size_t)(s * 256 + jH) * FIN + kw]
                        : 2.0f * Wf[(size_t)jH * FIN + kw];
        }
    }
    u16 hi = bf_hi(v);
    u16 lo = bf_hi(v - bf_f(hi));
    Bhi[idx] = hi;
    Blo[idx] = lo;
}

// ---------------------------------------------------------------------------
// Flat K-step decode: step s -> (G, ctl, B-kslot, A-kslot).
// ---------------------------------------------------------------------------
template<int NCT, bool LEAF>
__device__ __forceinline__ void kdecode(int s, int& G, int& ctl, int& sgB, int& sgA)
{
    constexpr int SUBS = NCT / 5;
    constexpr int TPG  = LEAF ? SUBS * 3 : SUBS * 4;
    constexpr int MAINS = (LEAF ? 2 : 10) * TPG;
    if (s < MAINS) {
        int g = s / TPG, tl = s % TPG;
        G = (LEAF ? 8 : 0) + g;
        ctl = LEAF ? (tl / 3) * 5 + (tl % 3) : (tl / 4) * 5 + (tl % 4);
        sgB = G;
        sgA = LEAF ? (G - 8) : G;
    } else {
        int s2 = s - MAINS;
        G = 10 + s2 / SUBS;
        ctl = (s2 % SUBS) * 5 + 4;
        sgB = G - 10;
        sgA = G;
    }
}

// ---------------------------------------------------------------------------
// One level unit (32 rows x (1280/CSPLIT) cols). Verbatim round-1 body.
// ---------------------------------------------------------------------------
template<int NCT, bool LEAF>
__device__ void do_level(int unit, char* smem,
    const float* __restrict__ feat,
    const u16* __restrict__ Bhi, const u16* __restrict__ Blo,
    const float* __restrict__ biou, const float* __restrict__ bfv,
    float* __restrict__ h, float* __restrict__ c,
    int Lt, int lg)
{
    constexpr int CSPLIT = 20 / NCT;
    constexpr int SUBS = NCT / 5;
    constexpr int KSTR = LEAF ? 2 : 18;                 // A kslot stride per row-tile
    short* Ahi = (short*)smem;
    short* Alo = (short*)(smem + (LEAF ? 4096 : 36864));

    const int tid = threadIdx.x;
    const int lane = tid & 63, w = tid >> 6;
    const int cs = unit % CSPLIT;
    const int rb = unit / CSPLIT;
    const int m0 = rb * 32;
    const int msk = (1 << lg) - 1;
    const int ctbase = cs * 4 * NCT + w * NCT;

    const float4* Hf4 = (const float4*)h;
    const float4* Ff4 = (const float4*)feat;

    // ---- stage A ----
    if constexpr (!LEAF) {
        for (int rep = 0; rep < 8; ++rep) {            // hs/hd: 32 m x 64 float4
            int flat = rep * 256 + tid;
            int m = flat >> 6, f4 = flat & 63;
            int mg = m0 + m;
            int b = mg >> lg, ii = Lt + (mg & msk);
            int gc = b * NPT + 2 * ii + 1;
            float4 h1 = Hf4[(size_t)gc * 64 + f4];
            float4 h2 = Hf4[(size_t)(gc + 1) * 64 + f4];
            float hsv[4] = {h1.x + h2.x, h1.y + h2.y, h1.z + h2.z, h1.w + h2.w};
            float hdv[4] = {h1.x - h2.x, h1.y - h2.y, h1.z - h2.z, h1.w - h2.w};
            int rt = m >> 4, lm = m & 15;
            int ks = f4 >> 3;
            int lane_ = lm + 16 * ((f4 >> 1) & 3);
            int j0 = (f4 & 1) * 4;
            ushort4 sh, sl, dh, dl;
            u16* shp = (u16*)&sh; u16* slp = (u16*)&sl;
            u16* dhp = (u16*)&dh; u16* dlp = (u16*)&dl;
#pragma unroll
            for (int e = 0; e < 4; ++e) {
                u16 a = bf_hi(hsv[e]); shp[e] = a; slp[e] = bf_hi(hsv[e] - bf_f(a));
                u16 d = bf_hi(hdv[e]); dhp[e] = d; dlp[e] = bf_hi(hdv[e] - bf_f(d));
            }
            int base_s = ((rt * 18 + ks) * 64 + lane_) * 8 + j0;        // hs at kstep ks
            int base_d = ((rt * 18 + ks + 10) * 64 + lane_) * 8 + j0;   // hd at kstep ks+10
            *(ushort4*)&Ahi[base_s] = sh;  *(ushort4*)&Alo[base_s] = sl;
            *(ushort4*)&Ahi[base_d] = dh;  *(ushort4*)&Alo[base_d] = dl;
        }
    }
    for (int rep = 0; rep < 2; ++rep) {                // x: 32 m x 16 float4
        int flat = rep * 256 + tid;
        int m = flat >> 4, f4 = flat & 15;
        int mg = m0 + m;
        int b = mg >> lg, ii = Lt + (mg & msk);
        int g = b * NPT + ii;
        float4 x4 = Ff4[(size_t)g * 16 + f4];
        float xv[4] = {x4.x, x4.y, x4.z, x4.w};
        int rt = m >> 4, lm = m & 15;
        int ks = (LEAF ? 0 : 8) + (f4 >> 3);
        int lane_ = lm + 16 * ((f4 >> 1) & 3);
        int j0 = (f4 & 1) * 4;
        ushort4 xh, xl;
        u16* xhp = (u16*)&xh; u16* xlp = (u16*)&xl;
#pragma unroll
        for (int e = 0; e < 4; ++e) {
            u16 a = bf_hi(xv[e]); xhp[e] = a; xlp[e] = bf_hi(xv[e] - bf_f(a));
        }
        int base = ((rt * KSTR + ks) * 64 + lane_) * 8 + j0;
        *(ushort4*)&Ahi[base] = xh;  *(ushort4*)&Alo[base] = xl;
    }
    __syncthreads();

    // ---- K loop (flat, software-pipelined) ----
    constexpr int TPG    = LEAF ? SUBS * 3 : SUBS * 4;
    constexpr int MAINS  = (LEAF ? 2 : 10) * TPG;
    constexpr int NSTEPS = LEAF ? MAINS : MAINS + 8 * SUBS;
    constexpr int NB = 6, PD = 5;                       // 6 rotating bufs, 5-deep prefetch
    constexpr int GLAST = LEAF ? 9 : 17;

    f32x4 acc[2][NCT];
#pragma unroll
    for (int rt = 0; rt < 2; ++rt)
#pragma unroll
        for (int i = 0; i < NCT; ++i) acc[rt][i] = (f32x4){0.f, 0.f, 0.f, 0.f};

    const u16* Bw_h = Bhi + (size_t)ctbase * 5120 + (size_t)lane * 8;
    const u16* Bw_l = Blo + (size_t)ctbase * 5120 + (size_t)lane * 8;
    const short* Ah0 = Ahi + lane * 8;
    const short* Al0 = Alo + lane * 8;

    bf16x8 bh[NB], bl[NB];
    bf16x8 pah[2][2], pal[2][2];

#pragma unroll
    for (int rt = 0; rt < 2; ++rt) {
        pah[0][rt] = *(const bf16x8*)&Ah0[(rt * KSTR + 0) * 512];
        pal[0][rt] = *(const bf16x8*)&Al0[(rt * KSTR + 0) * 512];
    }
#pragma unroll
    for (int p = 0; p < PD; ++p) {
        if (p < NSTEPS) {
            int G2, c2, b2, a2;
            kdecode<NCT, LEAF>(p, G2, c2, b2, a2);
            int off = (c2 * 10 + b2) * 512;
            bh[p % NB] = *(const bf16x8*)(Bw_h + off);
            bl[p % NB] = *(const bf16x8*)(Bw_l + off);
        }
    }

#pragma unroll
    for (int s = 0; s < NSTEPS; ++s) {
        int G, ctl, sgB, sgA;
        kdecode<NCT, LEAF>(s, G, ctl, sgB, sgA);
        bool firstG = (s < MAINS) ? (s % TPG == 0) : (((s - MAINS) % SUBS) == 0);
        if (firstG && G < GLAST) {
            int sgAn = LEAF ? (G - 7) : (G + 1);
            int parn = (G + 1) & 1;
#pragma unroll
            for (int rt = 0; rt < 2; ++rt) {
                pah[parn][rt] = *(const bf16x8*)&Ah0[(rt * KSTR + sgAn) * 512];
                pal[parn][rt] = *(const bf16x8*)&Al0[(rt * KSTR + sgAn) * 512];
            }
        }
        if (s + PD < NSTEPS) {
            int G2, c2, b2, a2;
            kdecode<NCT, LEAF>(s + PD, G2, c2, b2, a2);
            int off = (c2 * 10 + b2) * 512;
            bh[(s + PD) % NB] = *(const bf16x8*)(Bw_h + off);
            bl[(s + PD) % NB] = *(const bf16x8*)(Bw_l + off);
        }
        int par = G & 1;
#pragma unroll
        for (int rt = 0; rt < 2; ++rt) {
            acc[rt][ctl] = __builtin_amdgcn_mfma_f32_16x16x32_bf16(pah[par][rt], bh[s % NB], acc[rt][ctl], 0, 0, 0);
            acc[rt][ctl] = __builtin_amdgcn_mfma_f32_16x16x32_bf16(pah[par][rt], bl[s % NB], acc[rt][ctl], 0, 0, 0);
            acc[rt][ctl] = __builtin_amdgcn_mfma_f32_16x16x32_bf16(pal[par][rt], bh[s % NB], acc[rt][ctl], 0, 0, 0);
        }
    }
    __syncthreads();    // all waves done with A region; alias epilogue scratch over it

    // ---- epilogue (wave-private) ----
    float* sc = (float*)smem + w * 2592;       // [32 rows][81] fp32 per wave
    const int n = lane & 15, q = lane >> 4;
#pragma unroll
    for (int sub = 0; sub < SUBS; ++sub) {
#pragma unroll
        for (int rt = 0; rt < 2; ++rt)
#pragma unroll
            for (int s = 0; s < (LEAF ? 3 : 5); ++s) {
                f32x4 v = acc[rt][sub * 5 + s];
#pragma unroll
                for (int r = 0; r < 4; ++r)
                    sc[(rt * 16 + q * 4 + r) * 81 + s * 16 + n] = v[r];
            }
        int hb_abs = ctbase / 5 + sub;
        int jHb = hb_abs * 16;

        float c1v[8], c2v[8];
        if constexpr (!LEAF) {
#pragma unroll
            for (int it = 0; it < 8; ++it) {
                int idx = it * 64 + lane;
                int m = idx >> 4, jl = idx & 15;
                int jH = jHb + jl;
                int mg = m0 + m;
                int b = mg >> lg, ii = Lt + (mg & msk);
                size_t g = (size_t)b * NPT + ii;
                size_t gc = g + ii + 1;         // b*NPT + 2*ii + 1
                c1v[it] = c[gc * HH + jH];
                c2v[it] = c[(gc + 1) * HH + jH];
            }
        }
#pragma unroll
        for (int it = 0; it < 8; ++it) {
            int idx = it * 64 + lane;           // 512 items: 32 m x 16 jl
            int m = idx >> 4, jl = idx & 15;
            int jH = jHb + jl;
            float Ci  = sc[m * 81 + jl];
            float Co  = sc[m * 81 + 16 + jl];
            float Cu  = sc[m * 81 + 32 + jl];
            int mg = m0 + m;
            int b = mg >> lg, ii = Lt + (mg & msk);
            size_t g = (size_t)b * NPT + ii;
            float iv = sigf(Ci + biou[jH]);
            float ov = sigf(Co + biou[256 + jH]);
            float uv = tanh_fast(Cu + biou[512 + jH]);
            float cv;
            if constexpr (LEAF) {
                cv = iv * uv;
            } else {
                float Cfs = sc[m * 81 + 48 + jl];
                float Cfd = sc[m * 81 + 64 + jl];
                float bF = bfv[jH];
                float f1 = sigf(0.5f * (Cfs + Cfd) + bF);
                float f2 = sigf(0.5f * (Cfs - Cfd) + bF);
                cv = iv * uv + f1 * c1v[it] + f2 * c2v[it];
            }
            float hv = ov * tanh_fast(cv);
            c[g * HH + jH] = cv;
            h[g * HH + jH] = hv;
        }
    }
}

// ---------------------------------------------------------------------------
// Standalone level kernel (big levels: leaf, t1, t2).
// ---------------------------------------------------------------------------
template<int NCT, bool LEAF>
__global__ __launch_bounds__(256, LEAF ? 3 : 2) void level_mfma(
    const float* __restrict__ feat,
    const u16* __restrict__ Bhi, const u16* __restrict__ Blo,
    const float* __restrict__ biou, const float* __restrict__ bfv,
    float* __restrict__ h, float* __restrict__ c,
    int Lt, int lg)
{
    __shared__ char smem[LEAF ? 41472 : 73728];
    do_level<NCT, LEAF>(blockIdx.x, smem, feat, Bhi, Blo, biou, bfv, h, c, Lt, lg);
}

// ---------------------------------------------------------------------------
// Per-tree level, 512 threads = 8 waves x NCT=10 (proven register profile).
// One block owns one tree; M (<=16) nodes at ii=Lt..Lt+M-1; RT=1.
// Rolled over levels by the caller (runtime M/Lt -> ONE copy of this body).
// Rule-#20: epilogue prefetch uses compile-time-indexed c1v[4]/c2v[4] with
// runtime guards -> registers, no scratch (round-7's 36MB scratch bug).
// LDS: Ahi[18][64][8] @0 (18KB), Alo @18KB; epilogue scratch aliases @0
// (per wave [16][81] fp32 = 5184B x 8 waves = 41472B = full smem).
// ---------------------------------------------------------------------------
__device__ void tree_level10(int btree, int M, int Lt, char* smem,
    const float* __restrict__ feat,
    const u16* __restrict__ Bhi, const u16* __restrict__ Blo,
    const float* __restrict__ biou, const float* __restrict__ bfv,
    float* __restrict__ h, float* __restrict__ c)
{
    constexpr int NCT = 10;
    constexpr int SUBS = 2;
    short* Ahi = (short*)smem;
    short* Alo = (short*)(smem + 18432);

    __syncthreads();                         // prior level's scratch reads done

    const int tid = threadIdx.x;
    const int lane = tid & 63, w = tid >> 6;
    const int ctbase = w * NCT;              // waves 0..7 cover ct 0..79

    const float4* Hf4 = (const float4*)h;
    const float4* Ff4 = (const float4*)feat;

    // ---- stage A: hs/hd (M x 64 float4), kslots 0..7 and 10..17 ----
    for (int flat = tid; flat < M * 64; flat += 512) {
        int m = flat >> 6, f4 = flat & 63;
        int ii = Lt + m;
        int gc = btree * NPT + 2 * ii + 1;
        float4 h1 = Hf4[(size_t)gc * 64 + f4];
        float4 h2 = Hf4[(size_t)(gc + 1) * 64 + f4];
        float hsv[4] = {h1.x + h2.x, h1.y + h2.y, h1.z + h2.z, h1.w + h2.w};
        float hdv[4] = {h1.x - h2.x, h1.y - h2.y, h1.z - h2.z, h1.w - h2.w};
        int ks = f4 >> 3;
        int lane_ = m + 16 * ((f4 >> 1) & 3);
        int j0 = (f4 & 1) * 4;
        ushort4 sh, sl, dh, dl;
        u16* shp = (u16*)&sh; u16* slp = (u16*)&sl;
        u16* dhp = (u16*)&dh; u16* dlp = (u16*)&dl;
#pragma unroll
        for (int e = 0; e < 4; ++e) {
            u16 a = bf_hi(hsv[e]); shp[e] = a; slp[e] = bf_hi(hsv[e] - bf_f(a));
            u16 d = bf_hi(hdv[e]); dhp[e] = d; dlp[e] = bf_hi(hdv[e] - bf_f(d));
        }
        int base_s = (ks * 64 + lane_) * 8 + j0;
        int base_d = ((ks + 10) * 64 + lane_) * 8 + j0;
        *(ushort4*)&Ahi[base_s] = sh;  *(ushort4*)&Alo[base_s] = sl;
        *(ushort4*)&Ahi[base_d] = dh;  *(ushort4*)&Alo[base_d] = dl;
    }
    // ---- stage A: x rows (M x 16 float4), kslots 8..9 ----
    for (int flat = tid; flat < M * 16; flat += 512) {
        int m = flat >> 4, f4 = flat & 15;
        int g = btree * NPT + Lt + m;
        float4 x4 = Ff4[(size_t)g * 16 + f4];
        float xv[4] = {x4.x, x4.y, x4.z, x4.w};
        int ks = 8 + (f4 >> 3);
        int lane_ = m + 16 * ((f4 >> 1) & 3);
        int j0 = (f4 & 1) * 4;
        ushort4 xh, xl;
        u16* xhp = (u16*)&xh; u16* xlp = (u16*)&xl;
#pragma unroll
        for (int e = 0; e < 4; ++e) {
            u16 a = bf_hi(xv[e]); xhp[e] = a; xlp[e] = bf_hi(xv[e] - bf_f(a));
        }
        int base = (ks * 64 + lane_) * 8 + j0;
        *(ushort4*)&Ahi[base] = xh;  *(ushort4*)&Alo[base] = xl;
    }
    __syncthreads();

    // ---- K loop (flat, software-pipelined; RT=1, NCT=10 -> 96 steps) ----
    constexpr int TPG    = SUBS * 4;         // 8
    constexpr int MAINS  = 10 * TPG;         // 80
    constexpr int NSTEPS = MAINS + 8 * SUBS; // 96
    constexpr int NB = 6, PD = 5;
    constexpr int GLAST = 17;

    f32x4 acc[NCT];
#pragma unroll
    for (int i = 0; i < NCT; ++i) acc[i] = (f32x4){0.f, 0.f, 0.f, 0.f};

    const u16* Bw_h = Bhi + (size_t)ctbase * 5120 + (size_t)lane * 8;
    const u16* Bw_l = Blo + (size_t)ctbase * 5120 + (size_t)lane * 8;
    const short* Ah0 = Ahi + lane * 8;
    const short* Al0 = Alo + lane * 8;

    bf16x8 bh[NB], bl[NB];
    bf16x8 pah[2], pal[2];

    pah[0] = *(const bf16x8*)&Ah0[0];
    pal[0] = *(const bf16x8*)&Al0[0];
#pragma unroll
    for (int p = 0; p < PD; ++p) {
        int G2, c2, b2, a2;
        kdecode<NCT, false>(p, G2, c2, b2, a2);
        int off = (c2 * 10 + b2) * 512;
        bh[p % NB] = *(const bf16x8*)(Bw_h + off);
        bl[p % NB] = *(const bf16x8*)(Bw_l + off);
    }

#pragma unroll
    for (int s = 0; s < NSTEPS; ++s) {
        int G, ctl, sgB, sgA;
        kdecode<NCT, false>(s, G, ctl, sgB, sgA);
        bool firstG = (s < MAINS) ? (s % TPG == 0) : (((s - MAINS) % SUBS) == 0);
        if (firstG && G < GLAST) {
            int parn = (G + 1) & 1;
            pah[parn] = *(const bf16x8*)&Ah0[(G + 1) * 512];
            pal[parn] = *(const bf16x8*)&Al0[(G + 1) * 512];
        }
        if (s + PD < NSTEPS) {
            int G2, c2, b2, a2;
            kdecode<NCT, false>(s + PD, G2, c2, b2, a2);
            int off = (c2 * 10 + b2) * 512;
            bh[(s + PD) % NB] = *(const bf16x8*)(Bw_h + off);
            bl[(s + PD) % NB] = *(const bf16x8*)(Bw_l + off);
        }
        int par = G & 1;
        acc[ctl] = __builtin_amdgcn_mfma_f32_16x16x32_bf16(pah[par], bh[s % NB], acc[ctl], 0, 0, 0);
        acc[ctl] = __builtin_amdgcn_mfma_f32_16x16x32_bf16(pah[par], bl[s % NB], acc[ctl], 0, 0, 0);
        acc[ctl] = __builtin_amdgcn_mfma_f32_16x16x32_bf16(pal[par], bh[s % NB], acc[ctl], 0, 0, 0);
    }
    __syncthreads();    // all waves done with A region; alias scratch over it

    // ---- epilogue (wave-private, rows 0..M-1; compile-time-indexed bufs) ----
    float* sc = (float*)smem + w * 1296;       // [16 rows][81] fp32 per wave
    const int n = lane & 15, q = lane >> 4;
#pragma unroll
    for (int sub = 0; sub < SUBS; ++sub) {
#pragma unroll
        for (int s = 0; s < 5; ++s) {
            f32x4 v = acc[sub * 5 + s];
#pragma unroll
            for (int r = 0; r < 4; ++r)
                sc[(q * 4 + r) * 81 + s * 16 + n] = v[r];
        }
        int hb_abs = w * SUBS + sub;           // = ctbase/5 + sub
        int jHb = hb_abs * 16;

        float c1v[4], c2v[4];
#pragma unroll
        for (int it = 0; it < 4; ++it) {       // compile-time it -> registers
            int idx = it * 64 + lane;
            if (idx < M * 16) {
                int m = idx >> 4, jl = idx & 15;
                int jH = jHb + jl;
                int ii = Lt + m;
                size_t g = (size_t)btree * NPT + ii;
                size_t gc = g + ii + 1;        // btree*NPT + 2*ii + 1
                c1v[it] = c[gc * HH + jH];
                c2v[it] = c[(gc + 1) * HH + jH];
            }
        }
#pragma unroll
        for (int it = 0; it < 4; ++it) {
            int idx = it * 64 + lane;
            if (idx < M * 16) {
                int m = idx >> 4, jl = idx & 15;
                int jH = jHb + jl;
                int ii = Lt + m;
                size_t g = (size_t)btree * NPT + ii;
                float Ci  = sc[m * 81 + jl];
                float Co  = sc[m * 81 + 16 + jl];
                float Cu  = sc[m * 81 + 32 + jl];
                float Cfs = sc[m * 81 + 48 + jl];
                float Cfd = sc[m * 81 + 64 + jl];
                float iv = sigf(Ci + biou[jH]);
                float ov = sigf(Co + biou[256 + jH]);
                float uv = tanh_fast(Cu + biou[512 + jH]);
                float bF = bfv[jH];
                float f1 = sigf(0.5f * (Cfs + Cfd) + bF);
                float f2 = sigf(0.5f * (Cfs - Cfd) + bF);
                float cv = iv * uv + f1 * c1v[it] + f2 * c2v[it];
                float hv = ov * tanh_fast(cv);
                c[g * HH + jH] = cv;
                h[g * HH + jH] = hv;
            }
        }
    }
}

// ---------------------------------------------------------------------------
// Tree tail: t3..t7 + head; one 512-thread block per tree; NO grid sync.
// Level loop is rolled (one K-loop body in I$; runtime M/Lt).
// ---------------------------------------------------------------------------
__global__ __launch_bounds__(512, 2) void tree_tail(
    const float* __restrict__ feat,
    const u16* __restrict__ Bhi, const u16* __restrict__ Blo,
    const float* __restrict__ biou, const float* __restrict__ bfv,
    const float* __restrict__ l0w,  const float* __restrict__ l0b,
    const float* __restrict__ l1w,  const float* __restrict__ l1b,
    float* __restrict__ out,
    float* __restrict__ h, float* __restrict__ c)
{
    __shared__ char smem[41472];
    const int btree = blockIdx.x;
    const int tid = threadIdx.x;

    const int LtA[5] = {15, 7, 3, 1, 0};
    const int MA[5]  = {16, 8, 4, 2, 1};
#pragma unroll 1
    for (int lv = 0; lv < 5; ++lv)
        tree_level10(btree, MA[lv], LtA[lv], smem, feat, Bhi, Blo, biou, bfv, h, c);

    __syncthreads();

    // ---- head: threads 0..255 (bit-identical accumulation grouping);
    //      __syncthreads kept OUTSIDE divergent branches ----
    float* ms  = (float*)smem;         // 256 floats
    float* red = ms + HH;              // 4 floats
    const int j = tid & 255;
    const float* hb = h + (size_t)btree * NPT * HH;

    if (tid < 256) {
        float a0 = 0.f, a1 = 0.f, a2 = 0.f, a3 = 0.f;
        int i = 0;
        for (; i + 3 < NPT; i += 4) {
            a0 += hb[(size_t)(i    ) * HH + j];
            a1 += hb[(size_t)(i + 1) * HH + j];
            a2 += hb[(size_t)(i + 2) * HH + j];
            a3 += hb[(size_t)(i + 3) * HH + j];
        }
        a0 += hb[(size_t)252 * HH + j];
        a1 += hb[(size_t)253 * HH + j];
        a2 += hb[(size_t)254 * HH + j];
        ms[j] = (a0 + a1 + a2 + a3) * (1.0f / (float)NPT);
    }
    __syncthreads();

    if (tid < 256) {
        const float4* L0 = (const float4*)(l0w + (size_t)j * HH);
        const float4* M4 = (const float4*)ms;
        float y0 = 0.f, y1 = 0.f, y2 = 0.f, y3 = 0.f;
        for (int k4 = 0;  k4 < 16; ++k4) { float4 wv = L0[k4]; float4 m4 = M4[k4]; y0 += wv.x * m4.x + wv.y * m4.y + wv.z * m4.z + wv.w * m4.w; }
        for (int k4 = 16; k4 < 32; ++k4) { float4 wv = L0[k4]; float4 m4 = M4[k4]; y1 += wv.x * m4.x + wv.y * m4.y + wv.z * m4.z + wv.w * m4.w; }
        for (int k4 = 32; k4 < 48; ++k4) { float4 wv = L0[k4]; float4 m4 = M4[k4]; y2 += wv.x * m4.x + wv.y * m4.y + wv.z * m4.z + wv.w * m4.w; }
        for (int k4 = 48; k4 < 64; ++k4) { float4 wv = L0[k4]; float4 m4 = M4[k4]; y3 += wv.x * m4.x + wv.y * m4.y + wv.z * m4.z + wv.w * m4.w; }
        float yy = y0 + y1 + y2 + y3 + l0b[j];
        yy = fmaxf(yy, 0.f);
        float v = yy * l1w[j];
        for (int off = 32; off > 0; off >>= 1) v += __shfl_down(v, off, 64);
        if ((j & 63) == 0) red[j >> 6] = v;
    }
    __syncthreads();
    if (tid == 0) out[btree] = red[0] + red[1] + red[2] + red[3] + l1b[0];
}

// ---------------------------------------------------------------------------
extern "C" void kernel_launch(void* const* d_in, const int* in_sizes, int n_in,
                              void* d_out, int out_size, void* d_ws, size_t ws_size,
                              hipStream_t stream)
{
    const float* feat = (const float*)d_in[0];
    const float* Wiou = (const float*)d_in[4];
    const float* biou = (const float*)d_in[5];
    const float* Uiou = (const float*)d_in[6];
    const float* Wf   = (const float*)d_in[7];
    const float* bfv  = (const float*)d_in[8];
    const float* Uf   = (const float*)d_in[9];
    const float* l0w  = (const float*)d_in[10];
    const float* l0b  = (const float*)d_in[11];
    const float* l1w  = (const float*)d_in[12];
    const float* l1b  = (const float*)d_in[13];

    float* h = (float*)d_ws;
    float* c = h + (size_t)NTOT * HH;
    u16* Bhi = (u16*)(c + (size_t)NTOT * HH);
    u16* Blo = Bhi + 409600;

    // pack weights (every launch; ws is re-poisoned by harness)
    pack_B<<<1600, 256, 0, stream>>>(Uiou, Uf, Wiou, Wf, Bhi, Blo);

    // leaves: M=16384, NCT=10 (CSPLIT=2) -> 1024 blocks, 3 blocks/CU
    level_mfma<10, true><<<1024, 256, 0, stream>>>(feat, Bhi, Blo, biou, bfv, h, c, 127, 7);
    // t=1: M=8192, NCT=10 -> 512 blocks
    level_mfma<10, false><<<512, 256, 0, stream>>>(feat, Bhi, Blo, biou, bfv, h, c, 63, 6);
    // t=2: NCT=5 (CSPLIT=4) -> 512 blocks
    level_mfma<5, false><<<512, 256, 0, stream>>>(feat, Bhi, Blo, biou, bfv, h, c, 31, 5);

    // t=3..7 + head: one 512-thread block per tree, no grid sync
    tree_tail<<<B_TREES, 512, 0, stream>>>(feat, Bhi, Blo, biou, bfv,
                                           l0w, l0b, l1w, l1b, (float*)d_out,
                                           h, c);
}

// Round 9
// 375.697 us; speedup vs baseline: 2.7264x; 1.3719x over previous
//
#include <hip/hip_runtime.h>

#define B_TREES 128
#define NPT 255
#define NTOT (B_TREES * NPT)   // 32640
#define FIN 64
#define HH 256

typedef short bf16x8 __attribute__((ext_vector_type(8)));
typedef float f32x4  __attribute__((ext_vector_type(4)));
typedef unsigned short u16;

__device__ __forceinline__ float sigf(float x) {
    return __frcp_rn(1.0f + __expf(-x));
}
__device__ __forceinline__ float tanh_fast(float x) {
    return __builtin_fmaf(2.0f, sigf(2.0f * x), -1.0f);
}
__device__ __forceinline__ u16 bf_hi(float v) {       // round-to-nearest-even bf16
    unsigned u = __float_as_uint(v);
    return (u16)((u + 0x7FFFu + ((u >> 16) & 1u)) >> 16);
}
__device__ __forceinline__ float bf_f(u16 b) { return __uint_as_float(((unsigned)b) << 16); }

// ---------------------------------------------------------------------------
// B pack: B[576 x 1280] in MFMA-B-frag layout, split into bf16 hi + lo.
// ---------------------------------------------------------------------------
__global__ __launch_bounds__(256) void pack_B(
    const float* __restrict__ Uiou, const float* __restrict__ Uf,
    const float* __restrict__ Wiou, const float* __restrict__ Wf,
    u16* __restrict__ Bhi, u16* __restrict__ Blo)
{
    int idx = blockIdx.x * 256 + threadIdx.x;   // < 80*10*64*8 = 409600
    int j    = idx & 7;
    int lane = (idx >> 3) & 63;
    int ksl  = (idx >> 9) % 10;
    int ct   = idx / 5120;
    int s = ct % 5, hb = ct / 5;
    int n = lane & 15, q = lane >> 4;
    int jH = hb * 16 + n;
    int k = (s < 4 ? ksl * 32 : 320 + ksl * 32) + q * 8 + j;

    float v = 0.0f;
    if (s == 4) {
        if (k < 576) v = Uf[(size_t)jH * HH + (k - 320)];
    } else {
        if (k < 256) {
            v = (s < 3) ? Uiou[(size_t)(s * 256 + jH) * HH + k]
                        : Uf[(size_t)jH * HH + k];
        } else {
            int kw = k - 256;
            v = (s < 3) ? Wiou[(size_t)(s * 256 + jH) * FIN + kw]
                        : 2.0f * Wf[(size_t)jH * FIN + kw];
        }
    }
    u16 hi = bf_hi(v);
    u16 lo = bf_hi(v - bf_f(hi));
    Bhi[idx] = hi;
    Blo[idx] = lo;
}

// ---------------------------------------------------------------------------
// Flat K-step decode: step s -> (G, ctl, B-kslot, A-kslot). (unchanged)
// ---------------------------------------------------------------------------
template<int NCT, bool LEAF>
__device__ __forceinline__ void kdecode(int s, int& G, int& ctl, int& sgB, int& sgA)
{
    constexpr int SUBS = NCT / 5;
    constexpr int TPG  = LEAF ? SUBS * 3 : SUBS * 4;
    constexpr int MAINS = (LEAF ? 2 : 10) * TPG;
    if (s < MAINS) {
        int g = s / TPG, tl = s % TPG;
        G = (LEAF ? 8 : 0) + g;
        ctl = LEAF ? (tl / 3) * 5 + (tl % 3) : (tl / 4) * 5 + (tl % 4);
        sgB = G;
        sgA = LEAF ? (G - 8) : G;
    } else {
        int s2 = s - MAINS;
        G = 10 + s2 / SUBS;
        ctl = (s2 % SUBS) * 5 + 4;
        sgB = G - 10;
        sgA = G;
    }
}

// ---------------------------------------------------------------------------
// Level kernel, MB=16 rows/block, 256 threads = 4 waves x NCT col-tiles.
// LDS: A hi|lo = 36864B (16 x 576 x 2 x bf16) non-leaf, 4096B leaf;
// epilogue scratch (4 waves x [16][81] fp32 = 20736B) aliases A after barrier.
// 3 blocks/CU (launch_bounds(256,3): VGPR cap 170 -> no spill; LDS 3x36.9KB).
// acc[NCT] single row-tile: 40 AGPR for NCT=10. NB=4/PD=3 B prefetch.
// Per-output-element K-order, fragment math, gate chain identical to the
// round-1 kernel (MB=32, rt=2) -> bit-exact (absmax 0.0 expected).
// All loop bounds compile-time; M is always a multiple of 16 (no guards).
// ---------------------------------------------------------------------------
template<int NCT, bool LEAF>
__global__ __launch_bounds__(256, 3) void level16(
    const float* __restrict__ feat,
    const u16* __restrict__ Bhi, const u16* __restrict__ Blo,
    const float* __restrict__ biou, const float* __restrict__ bfv,
    float* __restrict__ h, float* __restrict__ c,
    int Lt, int lg)
{
    constexpr int CSPLIT = 20 / NCT;                   // 4 waves x NCT x CSPLIT = 80 ct
    constexpr int SUBS = NCT / 5;
    constexpr int AHI_ELEMS = LEAF ? 1024 : 9216;      // 16 rows x (64 | 576) K
    __shared__ char smem[LEAF ? 20736 : 36864];
    short* Ahi = (short*)smem;
    short* Alo = Ahi + AHI_ELEMS;

    const int tid = threadIdx.x;
    const int lane = tid & 63, w = tid >> 6;
    const int cs = blockIdx.x % CSPLIT;
    const int rb = blockIdx.x / CSPLIT;
    const int m0 = rb * 16;
    const int msk = (1 << lg) - 1;
    const int ctbase = cs * 4 * NCT + w * NCT;

    const float4* Hf4 = (const float4*)h;
    const float4* Ff4 = (const float4*)feat;

    // ---- stage A: hs/hd (16 m x 64 float4 = 1024 items, 4 reps) ----
    if constexpr (!LEAF) {
#pragma unroll
        for (int rep = 0; rep < 4; ++rep) {
            int flat = rep * 256 + tid;
            int m = flat >> 6, f4 = flat & 63;
            int mg = m0 + m;
            int b = mg >> lg, ii = Lt + (mg & msk);
            int gc = b * NPT + 2 * ii + 1;
            float4 h1 = Hf4[(size_t)gc * 64 + f4];
            float4 h2 = Hf4[(size_t)(gc + 1) * 64 + f4];
            float hsv[4] = {h1.x + h2.x, h1.y + h2.y, h1.z + h2.z, h1.w + h2.w};
            float hdv[4] = {h1.x - h2.x, h1.y - h2.y, h1.z - h2.z, h1.w - h2.w};
            int ks = f4 >> 3;
            int lane_ = m + 16 * ((f4 >> 1) & 3);
            int j0 = (f4 & 1) * 4;
            ushort4 sh, sl, dh, dl;
            u16* shp = (u16*)&sh; u16* slp = (u16*)&sl;
            u16* dhp = (u16*)&dh; u16* dlp = (u16*)&dl;
#pragma unroll
            for (int e = 0; e < 4; ++e) {
                u16 a = bf_hi(hsv[e]); shp[e] = a; slp[e] = bf_hi(hsv[e] - bf_f(a));
                u16 d = bf_hi(hdv[e]); dhp[e] = d; dlp[e] = bf_hi(hdv[e] - bf_f(d));
            }
            int base_s = (ks * 64 + lane_) * 8 + j0;            // hs at kslot ks
            int base_d = ((ks + 10) * 64 + lane_) * 8 + j0;     // hd at kslot ks+10
            *(ushort4*)&Ahi[base_s] = sh;  *(ushort4*)&Alo[base_s] = sl;
            *(ushort4*)&Ahi[base_d] = dh;  *(ushort4*)&Alo[base_d] = dl;
        }
    }
    {   // ---- stage A: x rows (16 m x 16 float4 = 256 items, 1 rep) ----
        int m = tid >> 4, f4 = tid & 15;
        int mg = m0 + m;
        int b = mg >> lg, ii = Lt + (mg & msk);
        int g = b * NPT + ii;
        float4 x4 = Ff4[(size_t)g * 16 + f4];
        float xv[4] = {x4.x, x4.y, x4.z, x4.w};
        int ks = (LEAF ? 0 : 8) + (f4 >> 3);
        int lane_ = m + 16 * ((f4 >> 1) & 3);
        int j0 = (f4 & 1) * 4;
        ushort4 xh, xl;
        u16* xhp = (u16*)&xh; u16* xlp = (u16*)&xl;
#pragma unroll
        for (int e = 0; e < 4; ++e) {
            u16 a = bf_hi(xv[e]); xhp[e] = a; xlp[e] = bf_hi(xv[e] - bf_f(a));
        }
        int base = (ks * 64 + lane_) * 8 + j0;
        *(ushort4*)&Ahi[base] = xh;  *(ushort4*)&Alo[base] = xl;
    }
    __syncthreads();

    // ---- K loop (flat, software-pipelined; single row-tile) ----
    constexpr int TPG    = LEAF ? SUBS * 3 : SUBS * 4;
    constexpr int MAINS  = (LEAF ? 2 : 10) * TPG;
    constexpr int NSTEPS = LEAF ? MAINS : MAINS + 8 * SUBS;
    constexpr int NB = 4, PD = 3;                       // 4 rotating bufs, 3-deep prefetch
    constexpr int GLAST = LEAF ? 9 : 17;

    f32x4 acc[NCT];
#pragma unroll
    for (int i = 0; i < NCT; ++i) acc[i] = (f32x4){0.f, 0.f, 0.f, 0.f};

    const u16* Bw_h = Bhi + (size_t)ctbase * 5120 + (size_t)lane * 8;
    const u16* Bw_l = Blo + (size_t)ctbase * 5120 + (size_t)lane * 8;
    const short* Ah0 = Ahi + lane * 8;
    const short* Al0 = Alo + lane * 8;

    bf16x8 bh[NB], bl[NB];
    bf16x8 pah[2], pal[2];

    // prologue: A frag for first G (parity 0), first PD B frags
    pah[0] = *(const bf16x8*)&Ah0[0];
    pal[0] = *(const bf16x8*)&Al0[0];
#pragma unroll
    for (int p = 0; p < PD; ++p) {
        if (p < NSTEPS) {
            int G2, c2, b2, a2;
            kdecode<NCT, LEAF>(p, G2, c2, b2, a2);
            int off = (c2 * 10 + b2) * 512;
            bh[p % NB] = *(const bf16x8*)(Bw_h + off);
            bl[p % NB] = *(const bf16x8*)(Bw_l + off);
        }
    }

#pragma unroll
    for (int s = 0; s < NSTEPS; ++s) {
        int G, ctl, sgB, sgA;
        kdecode<NCT, LEAF>(s, G, ctl, sgB, sgA);
        // A prefetch one G ahead (issued at first step of each G)
        bool firstG = (s < MAINS) ? (s % TPG == 0) : (((s - MAINS) % SUBS) == 0);
        if (firstG && G < GLAST) {
            int sgAn = LEAF ? (G - 7) : (G + 1);
            int parn = (G + 1) & 1;
            pah[parn] = *(const bf16x8*)&Ah0[sgAn * 512];
            pal[parn] = *(const bf16x8*)&Al0[sgAn * 512];
        }
        // B prefetch PD steps ahead
        if (s + PD < NSTEPS) {
            int G2, c2, b2, a2;
            kdecode<NCT, LEAF>(s + PD, G2, c2, b2, a2);
            int off = (c2 * 10 + b2) * 512;
            bh[(s + PD) % NB] = *(const bf16x8*)(Bw_h + off);
            bl[(s + PD) % NB] = *(const bf16x8*)(Bw_l + off);
        }
        int par = G & 1;
        acc[ctl] = __builtin_amdgcn_mfma_f32_16x16x32_bf16(pah[par], bh[s % NB], acc[ctl], 0, 0, 0);
        acc[ctl] = __builtin_amdgcn_mfma_f32_16x16x32_bf16(pah[par], bl[s % NB], acc[ctl], 0, 0, 0);
        acc[ctl] = __builtin_amdgcn_mfma_f32_16x16x32_bf16(pal[par], bh[s % NB], acc[ctl], 0, 0, 0);
    }
    __syncthreads();    // all waves done with A region; alias epilogue scratch over it

    // ---- epilogue (wave-private; all bounds compile-time) ----
    float* sc = (float*)smem + w * 1296;       // [16 rows][81] fp32 per wave
    const int n = lane & 15, q = lane >> 4;
#pragma unroll
    for (int sub = 0; sub < SUBS; ++sub) {
#pragma unroll
        for (int s5 = 0; s5 < (LEAF ? 3 : 5); ++s5) {
            f32x4 v = acc[sub * 5 + s5];
#pragma unroll
            for (int r = 0; r < 4; ++r)
                sc[(q * 4 + r) * 81 + s5 * 16 + n] = v[r];
        }
        int hb_abs = ctbase / 5 + sub;
        int jHb = hb_abs * 16;

        float c1v[4], c2v[4];
        if constexpr (!LEAF) {                 // prefetch children c (registers)
#pragma unroll
            for (int it = 0; it < 4; ++it) {
                int idx = it * 64 + lane;       // 256 items: 16 m x 16 jl
                int m = idx >> 4, jl = idx & 15;
                int jH = jHb + jl;
                int mg = m0 + m;
                int b = mg >> lg, ii = Lt + (mg & msk);
                size_t g = (size_t)b * NPT + ii;
                size_t gc = g + ii + 1;         // b*NPT + 2*ii + 1
                c1v[it] = c[gc * HH + jH];
                c2v[it] = c[(gc + 1) * HH + jH];
            }
        }
#pragma unroll
        for (int it = 0; it < 4; ++it) {
            int idx = it * 64 + lane;
            int m = idx >> 4, jl = idx & 15;
            int jH = jHb + jl;
            float Ci  = sc[m * 81 + jl];
            float Co  = sc[m * 81 + 16 + jl];
            float Cu  = sc[m * 81 + 32 + jl];
            int mg = m0 + m;
            int b = mg >> lg, ii = Lt + (mg & msk);
            size_t g = (size_t)b * NPT + ii;
            float iv = sigf(Ci + biou[jH]);
            float ov = sigf(Co + biou[256 + jH]);
            float uv = tanh_fast(Cu + biou[512 + jH]);
            float cv;
            if constexpr (LEAF) {
                cv = iv * uv;
            } else {
                float Cfs = sc[m * 81 + 48 + jl];
                float Cfd = sc[m * 81 + 64 + jl];
                float bF = bfv[jH];
                float f1 = sigf(0.5f * (Cfs + Cfd) + bF);
                float f2 = sigf(0.5f * (Cfs - Cfd) + bF);
                cv = iv * uv + f1 * c1v[it] + f2 * c2v[it];
            }
            float hv = ov * tanh_fast(cv);
            c[g * HH + jH] = cv;
            h[g * HH + jH] = hv;
        }
    }
}

// ---------------------------------------------------------------------------
// Head: 1024 threads/tree; mean over 255 h rows -> lin0 + ReLU -> lin1 dot.
// (round-1 verbatim, proven)
// ---------------------------------------------------------------------------
__global__ __launch_bounds__(1024) void head_wide(
    const float* __restrict__ h,
    const float* __restrict__ l0w, const float* __restrict__ l0b,
    const float* __restrict__ l1w, const float* __restrict__ l1b,
    float* __restrict__ out)
{
    __shared__ float ms[4][HH];
    __shared__ float part[4][HH];
    __shared__ float red[4];
    int b = blockIdx.x, tid = threadIdx.x;
    int j = tid & 255, g = tid >> 8;
    const float* hb = h + (size_t)b * NPT * HH;

    float a = 0.f;
    for (int i = g; i < NPT; i += 4) a += hb[(size_t)i * HH + j];
    ms[g][j] = a;
    __syncthreads();
    if (g == 0) ms[0][j] = (ms[0][j] + ms[1][j] + ms[2][j] + ms[3][j]) * (1.0f / (float)NPT);
    __syncthreads();

    const float4* L0 = (const float4*)(l0w + (size_t)j * HH);
    float y = 0.f;
    for (int k4 = 16 * g; k4 < 16 * (g + 1); ++k4) {
        float4 wv = L0[k4];
        float4 m4 = ((const float4*)ms[0])[k4];
        y += wv.x * m4.x + wv.y * m4.y + wv.z * m4.z + wv.w * m4.w;
    }
    part[g][j] = y;
    __syncthreads();

    if (g == 0) {
        float yy = part[0][j] + part[1][j] + part[2][j] + part[3][j] + l0b[j];
        yy = fmaxf(yy, 0.f);
        float v = yy * l1w[j];
        for (int off = 32; off > 0; off >>= 1) v += __shfl_down(v, off, 64);
        if ((j & 63) == 0) red[j >> 6] = v;
    }
    __syncthreads();
    if (tid == 0) out[b] = red[0] + red[1] + red[2] + red[3] + l1b[0];
}

// ---------------------------------------------------------------------------
extern "C" void kernel_launch(void* const* d_in, const int* in_sizes, int n_in,
                              void* d_out, int out_size, void* d_ws, size_t ws_size,
                              hipStream_t stream)
{
    const float* feat = (const float*)d_in[0];
    const float* Wiou = (const float*)d_in[4];
    const float* biou = (const float*)d_in[5];
    const float* Uiou = (const float*)d_in[6];
    const float* Wf   = (const float*)d_in[7];
    const float* bfv  = (const float*)d_in[8];
    const float* Uf   = (const float*)d_in[9];
    const float* l0w  = (const float*)d_in[10];
    const float* l0b  = (const float*)d_in[11];
    const float* l1w  = (const float*)d_in[12];
    const float* l1b  = (const float*)d_in[13];

    float* h = (float*)d_ws;
    float* c = h + (size_t)NTOT * HH;
    u16* Bhi = (u16*)(c + (size_t)NTOT * HH);
    u16* Blo = Bhi + 409600;

    // pack weights (every launch; ws is re-poisoned by harness)
    pack_B<<<1600, 256, 0, stream>>>(Uiou, Uf, Wiou, Wf, Bhi, Blo);

    // MB=16 levels: grid = (M/16) * CSPLIT
    level16<10, true ><<<2048, 256, 0, stream>>>(feat, Bhi, Blo, biou, bfv, h, c, 127, 7);
    level16<10, false><<<1024, 256, 0, stream>>>(feat, Bhi, Blo, biou, bfv, h, c, 63, 6);
    level16<5,  false><<<1024, 256, 0, stream>>>(feat, Bhi, Blo, biou, bfv, h, c, 31, 5);
    level16<5,  false><<<512,  256, 0, stream>>>(feat, Bhi, Blo, biou, bfv, h, c, 15, 4);
    level16<5,  false><<<256,  256, 0, stream>>>(feat, Bhi, Blo, biou, bfv, h, c, 7, 3);
    level16<5,  false><<<128,  256, 0, stream>>>(feat, Bhi, Blo, biou, bfv, h, c, 3, 2);
    level16<5,  false><<<64,   256, 0, stream>>>(feat, Bhi, Blo, biou, bfv, h, c, 1, 1);
    level16<5,  false><<<32,   256, 0, stream>>>(feat, Bhi, Blo, biou, bfv, h, c, 0, 0);

    head_wide<<<B_TREES, 1024, 0, stream>>>(h, l0w, l0b, l1w, l1b, (float*)d_out);
}

// Round 10
// 248.536 us; speedup vs baseline: 4.1213x; 1.5116x over previous
//
#include <hip/hip_runtime.h>

#define B_TREES 128
#define NPT 255
#define NTOT (B_TREES * NPT)   // 32640
#define FIN 64
#define HH 256

typedef short bf16x8 __attribute__((ext_vector_type(8)));
typedef float f32x4  __attribute__((ext_vector_type(4)));
typedef unsigned short u16;

__device__ __forceinline__ float sigf(float x) {
    return __frcp_rn(1.0f + __expf(-x));
}
__device__ __forceinline__ float tanh_fast(float x) {
    return __builtin_fmaf(2.0f, sigf(2.0f * x), -1.0f);
}
__device__ __forceinline__ u16 bf_hi(float v) {       // round-to-nearest-even bf16
    unsigned u = __float_as_uint(v);
    return (u16)((u + 0x7FFFu + ((u >> 16) & 1u)) >> 16);
}
__device__ __forceinline__ float bf_f(u16 b) { return __uint_as_float(((unsigned)b) << 16); }

// ---------------------------------------------------------------------------
// B pack: B[576 x 1280] in MFMA-B-frag layout, split into bf16 hi + lo.
// ---------------------------------------------------------------------------
__global__ __launch_bounds__(256) void pack_B(
    const float* __restrict__ Uiou, const float* __restrict__ Uf,
    const float* __restrict__ Wiou, const float* __restrict__ Wf,
    u16* __restrict__ Bhi, u16* __restrict__ Blo)
{
    int idx = blockIdx.x * 256 + threadIdx.x;   // < 80*10*64*8 = 409600
    int j    = idx & 7;
    int lane = (idx >> 3) & 63;
    int ksl  = (idx >> 9) % 10;
    int ct   = idx / 5120;
    int s = ct % 5, hb = ct / 5;
    int n = lane & 15, q = lane >> 4;
    int jH = hb * 16 + n;
    int k = (s < 4 ? ksl * 32 : 320 + ksl * 32) + q * 8 + j;

    float v = 0.0f;
    if (s == 4) {
        if (k < 576) v = Uf[(size_t)jH * HH + (k - 320)];
    } else {
        if (k < 256) {
            v = (s < 3) ? Uiou[(size_t)(s * 256 + jH) * HH + k]
                        : Uf[(size_t)jH * HH + k];
        } else {
            int kw = k - 256;
            v = (s < 3) ? Wiou[(size_t)(s * 256 + jH) * FIN + kw]
                        : 2.0f * Wf[(size_t)jH * FIN + kw];
        }
    }
    u16 hi = bf_hi(v);
    u16 lo = bf_hi(v - bf_f(hi));
    Bhi[idx] = hi;
    Blo[idx] = lo;
}

// ---------------------------------------------------------------------------
// Flat K-step decode: step s -> (G, ctl, B-kslot, A-kslot).
// Main region: G in [G0,10), tiles exclude s=4 (and s=3 for LEAF).
// Tail region (!LEAF only): G in [10,18), tiles s=4 only (B kslot = G-10).
// ---------------------------------------------------------------------------
template<int NCT, bool LEAF>
__device__ __forceinline__ void kdecode(int s, int& G, int& ctl, int& sgB, int& sgA)
{
    constexpr int SUBS = NCT / 5;
    constexpr int TPG  = LEAF ? SUBS * 3 : SUBS * 4;
    constexpr int MAINS = (LEAF ? 2 : 10) * TPG;
    if (s < MAINS) {
        int g = s / TPG, tl = s % TPG;
        G = (LEAF ? 8 : 0) + g;
        ctl = LEAF ? (tl / 3) * 5 + (tl % 3) : (tl / 4) * 5 + (tl % 4);
        sgB = G;
        sgA = LEAF ? (G - 8) : G;
    } else {
        int s2 = s - MAINS;
        G = 10 + s2 / SUBS;
        ctl = (s2 % SUBS) * 5 + 4;
        sgB = G - 10;
        sgA = G;
    }
}

// ---------------------------------------------------------------------------
// Level kernel (MFMA, split-bf16). 256 threads = 4 waves, MB = 32 nodes/block.
// Grid = rowblocks * CSPLIT;  CSPLIT = 20/NCT (cols split across blocks).
// Wave w covers NCT col-tiles: ctbase = cs*4*NCT + w*NCT.
// A[32 x 576] = [hs | x | hd] staged in LDS in A-frag layout (hi & lo).
// K-loop: flat software-pipelined stream over (G,ctl); B frags prefetched
// 5 steps ahead through 6 rotating reg buffers; A frags double-buffered by
// G-parity and prefetched one G ahead.
// LEAF: only x rows (A kslots rebased to {0,1}); s=3 (fs) and s=4 (fd) tiles
// skipped entirely (f gates unused at leaves); LDS shrunk to 41472 B
// -> 3 blocks/CU.
// Epilogue: per-wave private scratch (aliased over A after barrier); child-c
// loads prefetched into regs ahead of the gate chain.
// ---------------------------------------------------------------------------
template<int NCT, bool LEAF>
__global__ __launch_bounds__(256, LEAF ? 3 : 2) void level_mfma(
    const float* __restrict__ feat,
    const u16* __restrict__ Bhi, const u16* __restrict__ Blo,
    const float* __restrict__ biou, const float* __restrict__ bfv,
    float* __restrict__ h, float* __restrict__ c,
    int Lt, int lg)
{
    constexpr int CSPLIT = 20 / NCT;
    constexpr int SUBS = NCT / 5;
    constexpr int KSTR = LEAF ? 2 : 18;                 // A kslot stride per row-tile
    __shared__ char smem[LEAF ? 41472 : 73728];         // A_hi | A_lo ; aliased by epilogue scratch
    short* Ahi = (short*)smem;
    short* Alo = (short*)(smem + (LEAF ? 4096 : 36864));

    const int tid = threadIdx.x;
    const int lane = tid & 63, w = tid >> 6;
    const int cs = blockIdx.x % CSPLIT;
    const int rb = blockIdx.x / CSPLIT;
    const int m0 = rb * 32;
    const int msk = (1 << lg) - 1;
    const int ctbase = cs * 4 * NCT + w * NCT;

    const float4* Hf4 = (const float4*)h;
    const float4* Ff4 = (const float4*)feat;

    // ---- stage A ----
    if constexpr (!LEAF) {
        for (int rep = 0; rep < 8; ++rep) {            // hs/hd: 32 m x 64 float4
            int flat = rep * 256 + tid;
            int m = flat >> 6, f4 = flat & 63;
            int mg = m0 + m;
            int b = mg >> lg, ii = Lt + (mg & msk);
            int gc = b * NPT + 2 * ii + 1;
            float4 h1 = Hf4[(size_t)gc * 64 + f4];
            float4 h2 = Hf4[(size_t)(gc + 1) * 64 + f4];
            float hsv[4] = {h1.x + h2.x, h1.y + h2.y, h1.z + h2.z, h1.w + h2.w};
            float hdv[4] = {h1.x - h2.x, h1.y - h2.y, h1.z - h2.z, h1.w - h2.w};
            int rt = m >> 4, lm = m & 15;
            int ks = f4 >> 3;
            int lane_ = lm + 16 * ((f4 >> 1) & 3);
            int j0 = (f4 & 1) * 4;
            ushort4 sh, sl, dh, dl;
            u16* shp = (u16*)&sh; u16* slp = (u16*)&sl;
            u16* dhp = (u16*)&dh; u16* dlp = (u16*)&dl;
#pragma unroll
            for (int e = 0; e < 4; ++e) {
                u16 a = bf_hi(hsv[e]); shp[e] = a; slp[e] = bf_hi(hsv[e] - bf_f(a));
                u16 d = bf_hi(hdv[e]); dhp[e] = d; dlp[e] = bf_hi(hdv[e] - bf_f(d));
            }
            int base_s = ((rt * 18 + ks) * 64 + lane_) * 8 + j0;        // hs at kstep ks
            int base_d = ((rt * 18 + ks + 10) * 64 + lane_) * 8 + j0;   // hd at kstep ks+10
            *(ushort4*)&Ahi[base_s] = sh;  *(ushort4*)&Alo[base_s] = sl;
            *(ushort4*)&Ahi[base_d] = dh;  *(ushort4*)&Alo[base_d] = dl;
        }
    }
    for (int rep = 0; rep < 2; ++rep) {                // x: 32 m x 16 float4
        int flat = rep * 256 + tid;
        int m = flat >> 4, f4 = flat & 15;
        int mg = m0 + m;
        int b = mg >> lg, ii = Lt + (mg & msk);
        int g = b * NPT + ii;
        float4 x4 = Ff4[(size_t)g * 16 + f4];
        float xv[4] = {x4.x, x4.y, x4.z, x4.w};
        int rt = m >> 4, lm = m & 15;
        int ks = (LEAF ? 0 : 8) + (f4 >> 3);
        int lane_ = lm + 16 * ((f4 >> 1) & 3);
        int j0 = (f4 & 1) * 4;
        ushort4 xh, xl;
        u16* xhp = (u16*)&xh; u16* xlp = (u16*)&xl;
#pragma unroll
        for (int e = 0; e < 4; ++e) {
            u16 a = bf_hi(xv[e]); xhp[e] = a; xlp[e] = bf_hi(xv[e] - bf_f(a));
        }
        int base = ((rt * KSTR + ks) * 64 + lane_) * 8 + j0;
        *(ushort4*)&Ahi[base] = xh;  *(ushort4*)&Alo[base] = xl;
    }
    __syncthreads();

    // ---- K loop (flat, software-pipelined) ----
    constexpr int TPG    = LEAF ? SUBS * 3 : SUBS * 4;
    constexpr int MAINS  = (LEAF ? 2 : 10) * TPG;
    constexpr int NSTEPS = LEAF ? MAINS : MAINS + 8 * SUBS;
    constexpr int NB = 6, PD = 5;                       // 6 rotating bufs, 5-deep prefetch
    constexpr int GLAST = LEAF ? 9 : 17;

    f32x4 acc[2][NCT];
#pragma unroll
    for (int rt = 0; rt < 2; ++rt)
#pragma unroll
        for (int i = 0; i < NCT; ++i) acc[rt][i] = (f32x4){0.f, 0.f, 0.f, 0.f};

    const u16* Bw_h = Bhi + (size_t)ctbase * 5120 + (size_t)lane * 8;
    const u16* Bw_l = Blo + (size_t)ctbase * 5120 + (size_t)lane * 8;
    const short* Ah0 = Ahi + lane * 8;
    const short* Al0 = Alo + lane * 8;

    bf16x8 bh[NB], bl[NB];
    bf16x8 pah[2][2], pal[2][2];

    // prologue: A frags for first G (parity 0), first PD B frags
#pragma unroll
    for (int rt = 0; rt < 2; ++rt) {
        pah[0][rt] = *(const bf16x8*)&Ah0[(rt * KSTR + 0) * 512];
        pal[0][rt] = *(const bf16x8*)&Al0[(rt * KSTR + 0) * 512];
    }
#pragma unroll
    for (int p = 0; p < PD; ++p) {
        if (p < NSTEPS) {
            int G2, c2, b2, a2;
            kdecode<NCT, LEAF>(p, G2, c2, b2, a2);
            int off = (c2 * 10 + b2) * 512;
            bh[p % NB] = *(const bf16x8*)(Bw_h + off);
            bl[p % NB] = *(const bf16x8*)(Bw_l + off);
        }
    }

#pragma unroll
    for (int s = 0; s < NSTEPS; ++s) {
        int G, ctl, sgB, sgA;
        kdecode<NCT, LEAF>(s, G, ctl, sgB, sgA);
        // A prefetch one G ahead (issued at first step of each G)
        bool firstG = (s < MAINS) ? (s % TPG == 0) : (((s - MAINS) % SUBS) == 0);
        if (firstG && G < GLAST) {
            int sgAn = LEAF ? (G - 7) : (G + 1);
            int parn = (G + 1) & 1;
#pragma unroll
            for (int rt = 0; rt < 2; ++rt) {
                pah[parn][rt] = *(const bf16x8*)&Ah0[(rt * KSTR + sgAn) * 512];
                pal[parn][rt] = *(const bf16x8*)&Al0[(rt * KSTR + sgAn) * 512];
            }
        }
        // B prefetch PD steps ahead
        if (s + PD < NSTEPS) {
            int G2, c2, b2, a2;
            kdecode<NCT, LEAF>(s + PD, G2, c2, b2, a2);
            int off = (c2 * 10 + b2) * 512;
            bh[(s + PD) % NB] = *(const bf16x8*)(Bw_h + off);
            bl[(s + PD) % NB] = *(const bf16x8*)(Bw_l + off);
        }
        int par = G & 1;
#pragma unroll
        for (int rt = 0; rt < 2; ++rt) {
            acc[rt][ctl] = __builtin_amdgcn_mfma_f32_16x16x32_bf16(pah[par][rt], bh[s % NB], acc[rt][ctl], 0, 0, 0);
            acc[rt][ctl] = __builtin_amdgcn_mfma_f32_16x16x32_bf16(pah[par][rt], bl[s % NB], acc[rt][ctl], 0, 0, 0);
            acc[rt][ctl] = __builtin_amdgcn_mfma_f32_16x16x32_bf16(pal[par][rt], bh[s % NB], acc[rt][ctl], 0, 0, 0);
        }
    }
    __syncthreads();    // all waves done with A region; alias epilogue scratch over it

    // ---- epilogue (wave-private) ----
    float* sc = (float*)smem + w * 2592;       // [32 rows][81] fp32 per wave
    const int n = lane & 15, q = lane >> 4;
#pragma unroll
    for (int sub = 0; sub < SUBS; ++sub) {
        // write this sub's C tiles to scratch (LEAF: i/o/u only)
#pragma unroll
        for (int rt = 0; rt < 2; ++rt)
#pragma unroll
            for (int s = 0; s < (LEAF ? 3 : 5); ++s) {
                f32x4 v = acc[rt][sub * 5 + s];
#pragma unroll
                for (int r = 0; r < 4; ++r)
                    sc[(rt * 16 + q * 4 + r) * 81 + s * 16 + n] = v[r];
            }
        int hb_abs = ctbase / 5 + sub;
        int jHb = hb_abs * 16;

        float c1v[8], c2v[8];
        if constexpr (!LEAF) {                 // prefetch children c (16 independent loads)
#pragma unroll
            for (int it = 0; it < 8; ++it) {
                int idx = it * 64 + lane;
                int m = idx >> 4, jl = idx & 15;
                int jH = jHb + jl;
                int mg = m0 + m;
                int b = mg >> lg, ii = Lt + (mg & msk);
                size_t g = (size_t)b * NPT + ii;
                size_t gc = g + ii + 1;         // b*NPT + 2*ii + 1
                c1v[it] = c[gc * HH + jH];
                c2v[it] = c[(gc + 1) * HH + jH];
            }
        }
#pragma unroll
        for (int it = 0; it < 8; ++it) {
            int idx = it * 64 + lane;           // 512 items: 32 m x 16 jl
            int m = idx >> 4, jl = idx & 15;
            int jH = jHb + jl;
            float Ci  = sc[m * 81 + jl];
            float Co  = sc[m * 81 + 16 + jl];
            float Cu  = sc[m * 81 + 32 + jl];
            int mg = m0 + m;
            int b = mg >> lg, ii = Lt + (mg & msk);
            size_t g = (size_t)b * NPT + ii;
            float iv = sigf(Ci + biou[jH]);
            float ov = sigf(Co + biou[256 + jH]);
            float uv = tanh_fast(Cu + biou[512 + jH]);
            float cv;
            if constexpr (LEAF) {
                cv = iv * uv;
            } else {
                float Cfs = sc[m * 81 + 48 + jl];
                float Cfd = sc[m * 81 + 64 + jl];
                float bF = bfv[jH];
                float f1 = sigf(0.5f * (Cfs + Cfd) + bF);
                float f2 = sigf(0.5f * (Cfs - Cfd) + bF);
                cv = iv * uv + f1 * c1v[it] + f2 * c2v[it];
            }
            float hv = ov * tanh_fast(cv);
            c[g * HH + jH] = cv;
            h[g * HH + jH] = hv;
        }
    }
}

// ---------------------------------------------------------------------------
// Head: 1024 threads/tree; mean over 255 h rows -> lin0 + ReLU -> lin1 dot.
// ---------------------------------------------------------------------------
__global__ __launch_bounds__(1024) void head_wide(
    const float* __restrict__ h,
    const float* __restrict__ l0w, const float* __restrict__ l0b,
    const float* __restrict__ l1w, const float* __restrict__ l1b,
    float* __restrict__ out)
{
    __shared__ float ms[4][HH];
    __shared__ float part[4][HH];
    __shared__ float red[4];
    int b = blockIdx.x, tid = threadIdx.x;
    int j = tid & 255, g = tid >> 8;
    const float* hb = h + (size_t)b * NPT * HH;

    float a = 0.f;
    for (int i = g; i < NPT; i += 4) a += hb[(size_t)i * HH + j];
    ms[g][j] = a;
    __syncthreads();
    if (g == 0) ms[0][j] = (ms[0][j] + ms[1][j] + ms[2][j] + ms[3][j]) * (1.0f / (float)NPT);
    __syncthreads();

    const float4* L0 = (const float4*)(l0w + (size_t)j * HH);
    float y = 0.f;
    for (int k4 = 16 * g; k4 < 16 * (g + 1); ++k4) {
        float4 wv = L0[k4];
        float4 m4 = ((const float4*)ms[0])[k4];
        y += wv.x * m4.x + wv.y * m4.y + wv.z * m4.z + wv.w * m4.w;
    }
    part[g][j] = y;
    __syncthreads();

    if (g == 0) {
        float yy = part[0][j] + part[1][j] + part[2][j] + part[3][j] + l0b[j];
        yy = fmaxf(yy, 0.f);
        float v = yy * l1w[j];
        for (int off = 32; off > 0; off >>= 1) v += __shfl_down(v, off, 64);
        if ((j & 63) == 0) red[j >> 6] = v;
    }
    __syncthreads();
    if (tid == 0) out[b] = red[0] + red[1] + red[2] + red[3] + l1b[0];
}

// ---------------------------------------------------------------------------
extern "C" void kernel_launch(void* const* d_in, const int* in_sizes, int n_in,
                              void* d_out, int out_size, void* d_ws, size_t ws_size,
                              hipStream_t stream)
{
    const float* feat = (const float*)d_in[0];
    const float* Wiou = (const float*)d_in[4];
    const float* biou = (const float*)d_in[5];
    const float* Uiou = (const float*)d_in[6];
    const float* Wf   = (const float*)d_in[7];
    const float* bfv  = (const float*)d_in[8];
    const float* Uf   = (const float*)d_in[9];
    const float* l0w  = (const float*)d_in[10];
    const float* l0b  = (const float*)d_in[11];
    const float* l1w  = (const float*)d_in[12];
    const float* l1b  = (const float*)d_in[13];

    float* h = (float*)d_ws;
    float* c = h + (size_t)NTOT * HH;
    u16* Bhi = (u16*)(c + (size_t)NTOT * HH);
    u16* Blo = Bhi + 409600;

    // pack weights (every launch; ws is re-poisoned by harness)
    pack_B<<<1600, 256, 0, stream>>>(Uiou, Uf, Wiou, Wf, Bhi, Blo);

    // leaves: M=16384, NCT=10 (CSPLIT=2) -> 512*2 = 1024 blocks
    level_mfma<10, true><<<1024, 256, 0, stream>>>(feat, Bhi, Blo, biou, bfv, h, c, 127, 7);
    // t=1: M=8192, NCT=10 -> 256*2 = 512 blocks
    level_mfma<10, false><<<512, 256, 0, stream>>>(feat, Bhi, Blo, biou, bfv, h, c, 63, 6);
    // t=2..7: NCT=5 (CSPLIT=4)
    level_mfma<5, false><<<512, 256, 0, stream>>>(feat, Bhi, Blo, biou, bfv, h, c, 31, 5);
    level_mfma<5, false><<<256, 256, 0, stream>>>(feat, Bhi, Blo, biou, bfv, h, c, 15, 4);
    level_mfma<5, false><<<128, 256, 0, stream>>>(feat, Bhi, Blo, biou, bfv, h, c, 7, 3);
    level_mfma<5, false><<<64, 256, 0, stream>>>(feat, Bhi, Blo, biou, bfv, h, c, 3, 2);
    level_mfma<5, false><<<32, 256, 0, stream>>>(feat, Bhi, Blo, biou, bfv, h, c, 1, 1);
    level_mfma<5, false><<<16, 256, 0, stream>>>(feat, Bhi, Blo, biou, bfv, h, c, 0, 0);

    head_wide<<<B_TREES, 1024, 0, stream>>>(h, l0w, l0b, l1w, l1b, (float*)d_out);
}